// Round 16
// baseline (2024.051 us; speedup 1.0000x reference)
//
#include <hip/hip_runtime.h>
#include <cstdint>

typedef __attribute__((ext_vector_type(8))) _Float16 half8;  // 8 x fp16 (4 VGPRs)
typedef __attribute__((ext_vector_type(4))) _Float16 half4;  // 4 x fp16 (8B)
typedef __attribute__((ext_vector_type(4))) float f32x4;     // MFMA 16x16 accumulator
typedef unsigned short u16;
typedef unsigned int u32;
typedef unsigned long long u64;

#define MFMA16F(a, b, c) __builtin_amdgcn_mfma_f32_16x16x32_f16((a), (b), (c), 0, 0, 0)
#define AGENT __HIP_MEMORY_SCOPE_AGENT

// async global->LDS, 16B/lane. AUX: 0 = cached; 1 = SC0 (bypass L1, read own
// XCD L2 — r13-proven to see agent write-through stores from same XCD);
// 17 = SC0|SC1 (bypass L1+L2, read LLC — r11-proven for any XCD).
template <int AUX>
__device__ __forceinline__ void gl_lds16_a(const void* g, void* lds) {
  __builtin_amdgcn_global_load_lds(
      (const __attribute__((address_space(1))) unsigned*)g,
      (__attribute__((address_space(3))) unsigned*)lds, 16, 0, AUX);
}

__device__ __forceinline__ float sigm(float x) { return 1.f / (1.f + __expf(-x)); }
__device__ __forceinline__ float tanh_f(float x) { return 2.f / (1.f + __expf(-2.f * x)) - 1.f; }

// ---------------------------------------------------------------------------
__global__ void k_cvt(const float* __restrict__ in, _Float16* __restrict__ o, int n4) {
  int i = blockIdx.x * blockDim.x + threadIdx.x;
  int stride = gridDim.x * blockDim.x;
  for (; i < n4; i += stride) {
    float4 v = ((const float4*)in)[i];
    half4 h = {(_Float16)v.x, (_Float16)v.y, (_Float16)v.z, (_Float16)v.w};
    ((half4*)o)[i] = h;
  }
}

__global__ void k_bias(const float* __restrict__ bi, const float* __restrict__ bh,
                       float* __restrict__ bias) {
  int i = blockIdx.x * blockDim.x + threadIdx.x;
  if (i < 4096) bias[i] = bi[i] + bh[i];
}

// init h slots (256KB = 4 slots x 8 groups x 8KB): slot 0 = zeros (valid h(0),
// parity 0); slots 1-3 poisoned LSB=1. Also zero the 16 rendezvous words.
__global__ void k_init4(u64* __restrict__ hf, u32* __restrict__ rdz) {
  const int i = blockIdx.x * blockDim.x + threadIdx.x;  // 32768 u64
  const u64 v = (i < 8192) ? 0ull : 0x0001000100010001ull;
  __hip_atomic_store(&hf[i], v, __ATOMIC_RELAXED, AGENT);
  if (i < 16) __hip_atomic_store(&rdz[i], 0u, __ATOMIC_RELAXED, AGENT);
}

// ---------------------------------------------------------------------------
// GEMM1: xg = x.W_ih^T + bias  (M=16384, N=4096, K=1024), fp16 out in scan
// layout [l][s][j][gate]. m97 structure w/ 16B-slot XOR swizzle (r6-verified).
__global__ __launch_bounds__(256) void k_gemm1(
    const u16* __restrict__ Aw, const u16* __restrict__ Bw,
    const float* __restrict__ bias, _Float16* __restrict__ xg) {
  __shared__ u16 sA[4096];  // 8KB: 128 rows x 32 k (64B rows, swizzled 16B slots)
  __shared__ u16 sB[4096];
  const int tid = threadIdx.x, lane = tid & 63, wid = tid >> 6;
  const int bm = blockIdx.x >> 5, bn = blockIdx.x & 31;
  const int m0 = bm * 128, n0 = bn * 128;
  const int wr = wid >> 1, wc = wid & 1;
  f32x4 acc[4][4] = {};

  for (int kt = 0; kt < 32; ++kt) {
#pragma unroll
    for (int rb = 0; rb < 2; ++rb) {  // stage A+B: 2 rounds x 1KB per wave each
      const int base = (rb * 4 + wid) * 1024;
      const int b = base + lane * 16;
      const int row = b >> 6;                       // tile row
      const int q = lane & 3;                       // 16B slot in row
      const int sq = ((q - row) & 3) << 4;          // inverse-swizzled source slot
      gl_lds16_a<0>((const char*)Aw + (size_t)(m0 + row) * 2048 + (size_t)kt * 64 + sq,
                    (char*)&sA[0] + base);
      gl_lds16_a<0>((const char*)Bw + (size_t)(n0 + row) * 2048 + (size_t)kt * 64 + sq,
                    (char*)&sB[0] + base);
    }
    __syncthreads();
    half8 ah[4], bh[4];
#pragma unroll
    for (int i = 0; i < 4; ++i) {
      const int ra = wr * 64 + i * 16 + (lane & 15);
      ah[i] = *(const half8*)((const char*)sA + ra * 64 + ((((lane >> 4) + ra) & 3) << 4));
      const int rb2 = wc * 64 + i * 16 + (lane & 15);
      bh[i] = *(const half8*)((const char*)sB + rb2 * 64 + ((((lane >> 4) + rb2) & 3) << 4));
    }
#pragma unroll
    for (int i = 0; i < 4; ++i)
#pragma unroll
      for (int j = 0; j < 4; ++j) acc[i][j] = MFMA16F(ah[i], bh[j], acc[i][j]);
    __syncthreads();
  }

  // epilogue: C/D col=lane&15, row=(lane>>4)*4+q [m89]; scatter to [l][s][j][gate]
#pragma unroll
  for (int j = 0; j < 4; ++j) {
    const int gcol = n0 + wc * 64 + j * 16 + (lane & 15);
    const int gate = gcol >> 10, jj = gcol & 1023;
    const float bv = bias[gcol];
#pragma unroll
    for (int i = 0; i < 4; ++i)
#pragma unroll
      for (int q = 0; q < 4; ++q) {
        const int m = m0 + wr * 64 + i * 16 + (lane >> 4) * 4 + q;
        const int b = m >> 11, t = m & 2047;
        const int s = (b << 2) | (t & 3);
        const int l = t >> 2;
        xg[(((size_t)(l * 32 + s)) * 1024 + jj) * 4 + gate] = (_Float16)(acc[i][j][q] + bv);
      }
  }
}

// ---------------------------------------------------------------------------
// Persistent scan v12 = r14's proven skeleton (8 groups x 32 WGs x 512 thr,
// M=4, speculative data-as-flag, equality-vote rendezvous, adaptive aux=1/17,
// xg prefetch at loop end, NO sleep) + transpose-free gates (A=W rows
// p=c*4+gate, B=h -> acc[q] IS gate q) + 8 shallow MFMA chains + publish
// issued before the out store.
__global__ __launch_bounds__(512, 1) void k_scan(
    const u16* __restrict__ Whh16, const _Float16* __restrict__ xg,
    u16* __restrict__ hfrag, float* __restrict__ out, u32* __restrict__ rdz) {
  const int b = blockIdx.x;
  const int tid = threadIdx.x;
  const int lane = tid & 63, wid = tid >> 6;  // 8 waves

  __shared__ u16 h_lds[2][4096];  // 2 x 8KB double buffer
  __shared__ u32 sh_gr, sh_wl, sh_mode;

  // --- rendezvous (r14): always terminates (monotonic counter to 256) ---
  if (tid == 0) {
    u32 my;
    asm volatile("s_getreg_b32 %0, hwreg(HW_REG_XCC_ID)" : "=s"(my));
    my &= 7u;
    const u32 rank = __hip_atomic_fetch_add(&rdz[my], 1u, __ATOMIC_RELAXED, AGENT);
    __hip_atomic_fetch_add(&rdz[8], 1u, __ATOMIC_RELAXED, AGENT);
    while (__hip_atomic_load(&rdz[8], __ATOMIC_RELAXED, AGENT) < 256u)
      __builtin_amdgcn_s_sleep(1);
    u32 okloc = 1;
    for (int x = 0; x < 8; ++x)
      okloc &= (__hip_atomic_load(&rdz[x], __ATOMIC_RELAXED, AGENT) == 32u);
    sh_gr = okloc ? my : (u32)(b >> 5);
    sh_wl = okloc ? rank : (u32)(b & 31);
    sh_mode = okloc ? 0u : 1u;  // 0: own-L2 reads; 1: LLC reads
  }
  __syncthreads();
  const int gr = (int)sh_gr, wl = (int)sh_wl;
  int mode = (int)sh_mode;
  const int j0 = wl * 32;

  // stationary W fragments, rows p = c*4 + gate (transpose-free output)
  half8 wf[32];
  {
    const int p = lane & 15;
    const int gate = p & 3, c = p >> 2;
    const int koff = (lane >> 4) * 8;
    const size_t rowbase = (size_t)(gate * 1024 + j0 + wid * 4 + c) * 1024;
#pragma unroll
    for (int ks = 0; ks < 32; ++ks) {
      wf[ks] = *(const half8*)(Whh16 + rowbase + ks * 32 + koff);
      asm volatile("" : "+v"(wf[ks]));  // opaque: stays in register file
    }
  }

  // cell ownership: every lane computes (chain m=lane&3, col c=lane>>4);
  // lanes with (lane&12)!=0 are duplicates; act lanes do out-stores.
  const bool act = (lane & 12) == 0;
  const int m = lane & 3;
  const int jl = (wid << 2) | (lane >> 4);
  const int s = gr * 4 + m;
  const int j = j0 + jl;
  float c_reg = 0.f;
  const int hq = wl * 32 + m * 8 + wid;  // publish u64 idx (stored by lane<4)

  const u64 M = 0x0001000100010001ull;

  // xg pipeline: preload step 0 (raw half4; converted at use)
  half4 xv_cur = {};
  if (act) xv_cur = *(const half4*)(xg + ((size_t)s * 1024 + j) * 4);

  for (int l = 0; l < 512; ++l) {
    const char* hsrc = (const char*)hfrag + (size_t)(l & 3) * 65536 + gr * 8192;
    u64* hdst = (u64*)((char*)hfrag + (size_t)((l + 1) & 3) * 65536 + gr * 8192);
    const u64 expv = ((l >> 2) & 1) ? M : 0ull;     // expected read parity
    const u32 pw = (u32)(((l + 1) >> 2) & 1);       // publish parity
    u16* ldsb = &h_lds[l & 1][0];

    // --- speculative stage: ONE gl_lds16 per lane; retry until parity ok ---
    {
      int tries = 0;
      for (;;) {
        if (mode == 0)
          gl_lds16_a<1>(hsrc + wid * 1024 + lane * 16, (char*)ldsb + wid * 1024);
        else
          gl_lds16_a<17>(hsrc + wid * 1024 + lane * 16, (char*)ldsb + wid * 1024);
        asm volatile("s_waitcnt vmcnt(0)" ::: "memory");
        const u64* q = (const u64*)((const char*)ldsb + wid * 1024 + lane * 16);
        const bool ok = (((q[0] ^ expv) & M) == 0) & (((q[1] ^ expv) & M) == 0);
        if (__all(ok)) break;
        if (++tries > 64) mode = 1;  // permanent LLC fallback: liveness
      }
    }
    __syncthreads();  // the only per-step barrier

    // --- gates = W . h : 8 shallow chains (depth 4), W pinned ---
    f32x4 a0 = {0.f, 0.f, 0.f, 0.f}, a1 = a0, a2 = a0, a3 = a0;
    f32x4 a4 = a0, a5 = a0, a6 = a0, a7 = a0;
    const char* ab = (const char*)ldsb + (lane & 3) * 64 + (lane >> 4) * 16;
#pragma unroll
    for (int kt = 0; kt < 4; ++kt) {
      const char* cb = ab + kt * 2048;
      const int kw = kt * 8;
      a0 = MFMA16F(wf[kw], *(const half8*)(cb), a0);
      a1 = MFMA16F(wf[kw + 1], *(const half8*)(cb + 256), a1);
      a2 = MFMA16F(wf[kw + 2], *(const half8*)(cb + 512), a2);
      a3 = MFMA16F(wf[kw + 3], *(const half8*)(cb + 768), a3);
      a4 = MFMA16F(wf[kw + 4], *(const half8*)(cb + 1024), a4);
      a5 = MFMA16F(wf[kw + 5], *(const half8*)(cb + 1280), a5);
      a6 = MFMA16F(wf[kw + 6], *(const half8*)(cb + 1536), a6);
      a7 = MFMA16F(wf[kw + 7], *(const half8*)(cb + 1792), a7);
    }
    const f32x4 asum = ((a0 + a1) + (a2 + a3)) + ((a4 + a5) + (a6 + a7));
    // asum[q] = gate q for (chain=lane&3, col c=lane>>4) — no shfl transpose

    // --- LSTM cell (i,f,g,o) ---
    const float gi = asum[0] + (float)xv_cur[0], gf = asum[1] + (float)xv_cur[1];
    const float gg = asum[2] + (float)xv_cur[2], go = asum[3] + (float)xv_cur[3];
    const float iv = sigm(gi), fv = sigm(gf), gv = tanh_f(gg), ov = sigm(go);
    c_reg = fv * c_reg + iv * gv;
    const float hv = ov * tanh_f(c_reg);

    // --- publish FIRST: parity-forced u64 pack via shfl_xor 16/32, agent WT ---
    {
      u32 hb = (u32)__builtin_bit_cast(u16, (_Float16)hv);
      hb = (hb & 0xFFFEu) | pw;
      const u32 o1 = (u32)__shfl_xor((int)hb, 16);
      const u32 w1 = (lane & 16) ? ((o1 & 0xFFFFu) | (hb << 16))
                                 : ((hb & 0xFFFFu) | (o1 << 16));
      const u32 o2lo = (u32)__shfl_xor((int)w1, 32);
      const u64 v = (lane & 32) ? (((u64)w1 << 32) | (u64)o2lo)
                                : (((u64)o2lo << 32) | (u64)w1);
      if (lane < 4)
        __hip_atomic_store(&hdst[hq], v, __ATOMIC_RELAXED, AGENT);
    }

    if (act) {
      // out store (plain cached; ack absorbed by next stage's vmcnt)
      out[(((size_t)(s >> 2) * 2048) + (size_t)l * 4 + (s & 3)) * 1024 + j] = hv;
      // next-step xg prefetch (r14 position)
      if (l < 511)
        xv_cur = *(const half4*)(xg + (((size_t)(l + 1) * 32 + s) * 1024 + j) * 4);
    }
  }
}

// ---------------------------------------------------------------------------
extern "C" void kernel_launch(void* const* d_in, const int* in_sizes, int n_in,
                              void* d_out, int out_size, void* d_ws, size_t ws_size,
                              hipStream_t stream) {
  const float* x   = (const float*)d_in[0];
  const float* Wih = (const float*)d_in[1];
  const float* Whh = (const float*)d_in[2];
  const float* bih = (const float*)d_in[3];
  const float* bhh = (const float*)d_in[4];
  float* out = (float*)d_out;
  char* ws = (char*)d_ws;

  constexpr size_t OFF_WIH16 = 0;                 //  8388608
  constexpr size_t OFF_WHH16 = 8388608;           //  8388608
  constexpr size_t OFF_BIAS  = 16777216;          //    16384
  constexpr size_t OFF_HFRAG = 16793600;          //   262144 (4 slots x 8 groups x 8KB)
  constexpr size_t OFF_RDZ   = 17055744;          //       64
  constexpr size_t OFF_XG    = 17055808;          // 134217728 (fp16)
  constexpr size_t WS_NEED   = OFF_XG + 134217728;  // 151,273,536

  if (ws_size < WS_NEED) {  // canary: absmax reads exactly 0.9140625
    hipMemsetAsync(d_out, 0, (size_t)out_size * sizeof(float), stream);
    return;
  }

  _Float16* wih16 = (_Float16*)(ws + OFF_WIH16);
  _Float16* whh16 = (_Float16*)(ws + OFF_WHH16);
  float* bias = (float*)(ws + OFF_BIAS);
  u16* hfrag = (u16*)(ws + OFF_HFRAG);
  u32* rdz = (u32*)(ws + OFF_RDZ);
  _Float16* xg = (_Float16*)(ws + OFF_XG);
  // x16 scratch lives in d_out (67MB >= 33.5MB); scan fully overwrites out later
  _Float16* x16 = (_Float16*)d_out;

  k_cvt<<<1024, 256, 0, stream>>>(Wih, wih16, 4194304 / 4);
  k_cvt<<<1024, 256, 0, stream>>>(Whh, whh16, 4194304 / 4);
  k_cvt<<<2048, 256, 0, stream>>>(x, x16, 16777216 / 4);
  k_bias<<<16, 256, 0, stream>>>(bih, bhh, bias);
  k_init4<<<128, 256, 0, stream>>>((u64*)hfrag, rdz);
  k_gemm1<<<4096, 256, 0, stream>>>((const u16*)x16, (const u16*)wih16, bias, xg);
  k_scan<<<256, 512, 0, stream>>>((const u16*)whh16, xg, hfrag, out, rdz);
}

// Round 17
// 1364.876 us; speedup vs baseline: 1.4830x; 1.4830x over previous
//
#include <hip/hip_runtime.h>
#include <cstdint>

typedef __attribute__((ext_vector_type(8))) _Float16 half8;  // 8 x fp16 (4 VGPRs)
typedef __attribute__((ext_vector_type(4))) _Float16 half4;  // 4 x fp16 (8B)
typedef __attribute__((ext_vector_type(4))) float f32x4;     // MFMA 16x16 accumulator
typedef unsigned short u16;
typedef unsigned int u32;
typedef unsigned long long u64;

#define MFMA16F(a, b, c) __builtin_amdgcn_mfma_f32_16x16x32_f16((a), (b), (c), 0, 0, 0)
#define AGENT __HIP_MEMORY_SCOPE_AGENT

// cached async global->LDS, 16B/lane (GEMM staging)
__device__ __forceinline__ void gl_lds16(const void* g, void* lds) {
  __builtin_amdgcn_global_load_lds(
      (const __attribute__((address_space(1))) unsigned*)g,
      (__attribute__((address_space(3))) unsigned*)lds, 16, 0, 0);
}

__device__ __forceinline__ float sigm(float x) { return 1.f / (1.f + __expf(-x)); }
__device__ __forceinline__ float tanh_f(float x) { return 2.f / (1.f + __expf(-2.f * x)) - 1.f; }

// ---------------------------------------------------------------------------
__global__ void k_cvt(const float* __restrict__ in, _Float16* __restrict__ o, int n4) {
  int i = blockIdx.x * blockDim.x + threadIdx.x;
  int stride = gridDim.x * blockDim.x;
  for (; i < n4; i += stride) {
    float4 v = ((const float4*)in)[i];
    half4 h = {(_Float16)v.x, (_Float16)v.y, (_Float16)v.z, (_Float16)v.w};
    ((half4*)o)[i] = h;
  }
}

__global__ void k_bias(const float* __restrict__ bi, const float* __restrict__ bh,
                       float* __restrict__ bias) {
  int i = blockIdx.x * blockDim.x + threadIdx.x;
  if (i < 4096) bias[i] = bi[i] + bh[i];
}

// init h slots (256KB total): slot 0 = zeros (valid h(0), parity 0); slots 1-3
// poisoned LSB=1. agent-scope so the scan's coherent loads see it.
__global__ void k_init4(u64* __restrict__ hf) {
  const int i = blockIdx.x * blockDim.x + threadIdx.x;  // 32768 u64
  const u64 v = (i < 8192) ? 0ull : 0x0001000100010001ull;
  __hip_atomic_store(&hf[i], v, __ATOMIC_RELAXED, AGENT);
}

// ---------------------------------------------------------------------------
// GEMM1: xg = x.W_ih^T + bias  (M=16384, N=4096, K=1024), fp16 out in scan
// layout [l][s][j][gate]. m97 structure w/ 16B-slot XOR swizzle (r6-verified).
__global__ __launch_bounds__(256) void k_gemm1(
    const u16* __restrict__ Aw, const u16* __restrict__ Bw,
    const float* __restrict__ bias, _Float16* __restrict__ xg) {
  __shared__ u16 sA[4096];  // 8KB: 128 rows x 32 k (64B rows, swizzled 16B slots)
  __shared__ u16 sB[4096];
  const int tid = threadIdx.x, lane = tid & 63, wid = tid >> 6;
  const int bm = blockIdx.x >> 5, bn = blockIdx.x & 31;
  const int m0 = bm * 128, n0 = bn * 128;
  const int wr = wid >> 1, wc = wid & 1;
  f32x4 acc[4][4] = {};

  for (int kt = 0; kt < 32; ++kt) {
#pragma unroll
    for (int rb = 0; rb < 2; ++rb) {  // stage A+B: 2 rounds x 1KB per wave each
      const int base = (rb * 4 + wid) * 1024;
      const int b = base + lane * 16;
      const int row = b >> 6;                       // tile row
      const int q = lane & 3;                       // 16B slot in row
      const int sq = ((q - row) & 3) << 4;          // inverse-swizzled source slot
      gl_lds16((const char*)Aw + (size_t)(m0 + row) * 2048 + (size_t)kt * 64 + sq,
               (char*)&sA[0] + base);
      gl_lds16((const char*)Bw + (size_t)(n0 + row) * 2048 + (size_t)kt * 64 + sq,
               (char*)&sB[0] + base);
    }
    __syncthreads();
    half8 ah[4], bh[4];
#pragma unroll
    for (int i = 0; i < 4; ++i) {
      const int ra = wr * 64 + i * 16 + (lane & 15);
      ah[i] = *(const half8*)((const char*)sA + ra * 64 + ((((lane >> 4) + ra) & 3) << 4));
      const int rb2 = wc * 64 + i * 16 + (lane & 15);
      bh[i] = *(const half8*)((const char*)sB + rb2 * 64 + ((((lane >> 4) + rb2) & 3) << 4));
    }
#pragma unroll
    for (int i = 0; i < 4; ++i)
#pragma unroll
      for (int j = 0; j < 4; ++j) acc[i][j] = MFMA16F(ah[i], bh[j], acc[i][j]);
    __syncthreads();
  }

  // epilogue: C/D col=lane&15, row=(lane>>4)*4+q [m89]; scatter to [l][s][j][gate]
#pragma unroll
  for (int j = 0; j < 4; ++j) {
    const int gcol = n0 + wc * 64 + j * 16 + (lane & 15);
    const int gate = gcol >> 10, jj = gcol & 1023;
    const float bv = bias[gcol];
#pragma unroll
    for (int i = 0; i < 4; ++i)
#pragma unroll
      for (int q = 0; q < 4; ++q) {
        const int m = m0 + wr * 64 + i * 16 + (lane >> 4) * 4 + q;
        const int b = m >> 11, t = m & 2047;
        const int s = (b << 2) | (t & 3);
        const int l = t >> 2;
        xg[(((size_t)(l * 32 + s)) * 1024 + jj) * 4 + gate] = (_Float16)(acc[i][j][q] + bv);
      }
  }
}

// ---------------------------------------------------------------------------
// Persistent scan v13 = r11's proven kernel (1267us) with ONE change:
// register-staged probe. Each lane loads its 32B share as 4 x u64 relaxed
// agent atomic loads (the exact load type the r2-r8 flag barriers proved
// fresh against cross-XCD write-through stores), checks parity IN REGISTERS
// (no LDS read-back on the detect path), retries on mismatch, and only on
// success writes the 32B to LDS (drained by the existing __syncthreads).
// Topology: 4 groups x 32 WGs x 512 thr (8 waves), M=8; parity LSB in
// payload, 4 rotating slots, ONE barrier per step. No sentinel, no flags.
__global__ __launch_bounds__(512, 1) void k_scan(
    const u16* __restrict__ Whh16, const _Float16* __restrict__ xg,
    u16* __restrict__ hfrag, float* __restrict__ out) {
  __shared__ u16 h_lds[2][8192];  // 2 x 16KB double buffer
  const int tid = threadIdx.x;
  const int lane = tid & 63, wid = tid >> 6;  // 8 waves
  const int w = blockIdx.x;
  const int gr = w >> 5;         // group (0..3)
  const int wl = w & 31;         // WG id within group
  const int j0 = wl * 32;        // 32 hidden cols

  // stationary W fragments: lane p=lane&15 -> gate=p>>2, local col c=p&3;
  // wave's 4 cols are j0 + 4*wid + c. 128 VGPRs, pinned opaque.
  half8 wf[32];
  {
    const int p = lane & 15;
    const int gate = p >> 2, c = p & 3;
    const int koff = (lane >> 4) * 8;
    const size_t rowbase = (size_t)(gate * 1024 + j0 + wid * 4 + c) * 1024;
#pragma unroll
    for (int ks = 0; ks < 32; ++ks) {
      wf[ks] = *(const half8*)(Whh16 + rowbase + ks * 32 + koff);
      asm volatile("" : "+v"(wf[ks]));  // opaque: stays in register file
    }
  }

  // cell ownership (lanes 0-31 only; 32-63 hold duplicate MFMA rows)
  const int m = ((lane >> 4) << 2) | ((lane >> 2) & 3);  // chain (local, 0..7)
  const int jl = (wid << 2) | (lane & 3);                // local hidden col (0..31)
  const int s = gr * 8 + m;                              // global chain
  const int j = j0 + jl;                                 // global hidden col
  float c_reg = 0.f;
  const int hq = wl * 64 + (wid >> 1) * 16 + m * 2 + (wid & 1);

  const u64 M = 0x0001000100010001ull;

  // xg pipeline: preload step 0 (8B: 4 gates innermost), lanes 0-31
  float x0 = 0.f, x1 = 0.f, x2 = 0.f, x3 = 0.f;
  if (lane < 32) {
    const half4 xv = *(const half4*)(xg + ((size_t)s * 1024 + j) * 4);
    x0 = (float)xv[0]; x1 = (float)xv[1]; x2 = (float)xv[2]; x3 = (float)xv[3];
  }

  for (int l = 0; l < 512; ++l) {
    const char* hsrc = (const char*)hfrag + (size_t)(l & 3) * 65536 + gr * 16384;
    u64* hdst = (u64*)((char*)hfrag + (size_t)((l + 1) & 3) * 65536 + gr * 16384);
    const u64 expv = ((l >> 2) & 1) ? M : 0ull;     // expected read parity
    const u32 pw = (u32)(((l + 1) >> 2) & 1);       // publish parity
    u16* ldsb = &h_lds[l & 1][0];

    // --- register-staged probe: 4 x u64 agent loads, parity check in regs ---
    u64 q0, q1, q2, q3;
    {
      const u64* gsrc = (const u64*)(hsrc + wid * 2048 + lane * 32);
      for (;;) {
        q0 = __hip_atomic_load(gsrc + 0, __ATOMIC_RELAXED, AGENT);
        q1 = __hip_atomic_load(gsrc + 1, __ATOMIC_RELAXED, AGENT);
        q2 = __hip_atomic_load(gsrc + 2, __ATOMIC_RELAXED, AGENT);
        q3 = __hip_atomic_load(gsrc + 3, __ATOMIC_RELAXED, AGENT);
        const bool ok = (((q0 ^ expv) & M) == 0) & (((q1 ^ expv) & M) == 0) &
                        (((q2 ^ expv) & M) == 0) & (((q3 ^ expv) & M) == 0);
        if (__all(ok)) break;
      }
      u64* dst = (u64*)((char*)ldsb + wid * 2048 + lane * 32);
      dst[0] = q0; dst[1] = q1; dst[2] = q2; dst[3] = q3;
    }
    __syncthreads();  // the only per-step barrier (drains lgkm for MFMA reads)

    // --- gates = h . W^T : 4 independent accumulator chains, W pinned ---
    // A-frag read: ks*512 + (lane>>4)*128 + (lane&7)*16 (rows 8-15 duplicate)
    f32x4 a0 = {0.f, 0.f, 0.f, 0.f}, a1 = a0, a2 = a0, a3 = a0;
    const char* ab = (const char*)ldsb + (lane >> 4) * 128 + (lane & 7) * 16;
#pragma unroll
    for (int ks = 0; ks < 32; ks += 4) {
      const char* cb = ab + ks * 512;
      a0 = MFMA16F(*(const half8*)(cb), wf[ks], a0);
      a1 = MFMA16F(*(const half8*)(cb + 512), wf[ks + 1], a1);
      a2 = MFMA16F(*(const half8*)(cb + 1024), wf[ks + 2], a2);
      a3 = MFMA16F(*(const half8*)(cb + 1536), wf[ks + 3], a3);
    }
    float G0 = (a0[0] + a1[0]) + (a2[0] + a3[0]);
    float G1 = (a0[1] + a1[1]) + (a2[1] + a3[1]);
    float G2 = (a0[2] + a1[2]) + (a2[2] + a3[2]);
    float G3 = (a0[3] + a1[3]) + (a2[3] + a3[3]);

    // --- 4x4 lane/register transpose (lane bits 2-3 <-> reg bits) ---
    {
      const bool h2 = (lane & 4) != 0;
      float x, y;
      x = h2 ? G0 : G1; y = __shfl_xor(x, 4);
      G0 = h2 ? y : G0; G1 = h2 ? G1 : y;
      x = h2 ? G2 : G3; y = __shfl_xor(x, 4);
      G2 = h2 ? y : G2; G3 = h2 ? G3 : y;
    }
    {
      const bool h3 = (lane & 8) != 0;
      float x, y;
      x = h3 ? G0 : G2; y = __shfl_xor(x, 8);
      G0 = h3 ? y : G0; G2 = h3 ? G2 : y;
      x = h3 ? G1 : G3; y = __shfl_xor(x, 8);
      G1 = h3 ? y : G1; G3 = h3 ? G3 : y;
    }

    // --- LSTM cell (i,f,g,o) ---
    const float gi = G0 + x0, gf = G1 + x1, gg = G2 + x2, go = G3 + x3;
    const float iv = sigm(gi), fv = sigm(gf), gv = tanh_f(gg), ov = sigm(go);
    c_reg = fv * c_reg + iv * gv;
    const float hv = ov * tanh_f(c_reg);

    if (lane < 32) {
      // --- publish FIRST (peers' critical path): parity-forced u64 pack ---
      u32 hb = (u32)__builtin_bit_cast(u16, (_Float16)hv);
      hb = (hb & 0xFFFEu) | pw;
      const u32 o1 = (u32)__shfl_xor((int)hb, 1);
      const u32 w1 = (lane & 1) ? ((o1 & 0xFFFFu) | (hb << 16))
                                : ((hb & 0xFFFFu) | (o1 << 16));
      const u32 o2lo = (u32)__shfl_xor((int)w1, 2);
      const u64 v = (lane & 2) ? (((u64)w1 << 32) | (u64)o2lo)
                               : (((u64)o2lo << 32) | (u64)w1);
      if ((lane & 3) == 0)
        __hip_atomic_store(&hdst[hq], v, __ATOMIC_RELAXED, AGENT);

      // out store (plain cached; ack overlaps next probe)
      out[(((size_t)(s >> 2) * 2048) + (size_t)l * 4 + (s & 3)) * 1024 + j] = hv;

      // next-step xg prefetch
      if (l < 511) {
        const half4 xv = *(const half4*)(xg + (((size_t)(l + 1) * 32 + s) * 1024 + j) * 4);
        x0 = (float)xv[0]; x1 = (float)xv[1]; x2 = (float)xv[2]; x3 = (float)xv[3];
      }
    }
  }
}

// ---------------------------------------------------------------------------
extern "C" void kernel_launch(void* const* d_in, const int* in_sizes, int n_in,
                              void* d_out, int out_size, void* d_ws, size_t ws_size,
                              hipStream_t stream) {
  const float* x   = (const float*)d_in[0];
  const float* Wih = (const float*)d_in[1];
  const float* Whh = (const float*)d_in[2];
  const float* bih = (const float*)d_in[3];
  const float* bhh = (const float*)d_in[4];
  float* out = (float*)d_out;
  char* ws = (char*)d_ws;

  constexpr size_t OFF_WIH16 = 0;                 //  8388608
  constexpr size_t OFF_WHH16 = 8388608;           //  8388608
  constexpr size_t OFF_BIAS  = 16777216;          //    16384
  constexpr size_t OFF_HFRAG = 16793600;          //   262144 (4 slots x 4 groups x 16KB)
  constexpr size_t OFF_XG    = 17055744;          // 134217728 (fp16)
  constexpr size_t WS_NEED   = OFF_XG + 134217728;  // 151,273,472

  if (ws_size < WS_NEED) {  // canary: absmax reads exactly 0.9140625
    hipMemsetAsync(d_out, 0, (size_t)out_size * sizeof(float), stream);
    return;
  }

  _Float16* wih16 = (_Float16*)(ws + OFF_WIH16);
  _Float16* whh16 = (_Float16*)(ws + OFF_WHH16);
  float* bias = (float*)(ws + OFF_BIAS);
  u16* hfrag = (u16*)(ws + OFF_HFRAG);
  _Float16* xg = (_Float16*)(ws + OFF_XG);
  // x16 scratch lives in d_out (67MB >= 33.5MB); scan fully overwrites out later
  _Float16* x16 = (_Float16*)d_out;

  k_cvt<<<1024, 256, 0, stream>>>(Wih, wih16, 4194304 / 4);
  k_cvt<<<1024, 256, 0, stream>>>(Whh, whh16, 4194304 / 4);
  k_cvt<<<2048, 256, 0, stream>>>(x, x16, 16777216 / 4);
  k_bias<<<16, 256, 0, stream>>>(bih, bhh, bias);
  k_init4<<<128, 256, 0, stream>>>((u64*)hfrag);
  k_gemm1<<<4096, 256, 0, stream>>>((const u16*)x16, (const u16*)wih16, bias, xg);
  k_scan<<<128, 512, 0, stream>>>((const u16*)whh16, xg, hfrag, out);
}

// Round 18
// 1265.789 us; speedup vs baseline: 1.5990x; 1.0783x over previous
//
#include <hip/hip_runtime.h>
#include <cstdint>

typedef __attribute__((ext_vector_type(8))) _Float16 half8;  // 8 x fp16 (4 VGPRs)
typedef __attribute__((ext_vector_type(4))) _Float16 half4;  // 4 x fp16 (8B)
typedef __attribute__((ext_vector_type(4))) float f32x4;     // MFMA 16x16 accumulator
typedef unsigned short u16;
typedef unsigned int u32;
typedef unsigned long long u64;

#define MFMA16F(a, b, c) __builtin_amdgcn_mfma_f32_16x16x32_f16((a), (b), (c), 0, 0, 0)
#define AGENT __HIP_MEMORY_SCOPE_AGENT

// async global->LDS, 16B/lane, aux=17 (SC0|SC1): bypass L1+L2, read at the
// device coherence point -> sees agent-scope write-through stores (r11-proven).
__device__ __forceinline__ void gl_lds16_coh(const void* g, void* lds) {
  __builtin_amdgcn_global_load_lds(
      (const __attribute__((address_space(1))) unsigned*)g,
      (__attribute__((address_space(3))) unsigned*)lds, 16, 0, 17);
}
// cached variant (read-only data)
__device__ __forceinline__ void gl_lds16(const void* g, void* lds) {
  __builtin_amdgcn_global_load_lds(
      (const __attribute__((address_space(1))) unsigned*)g,
      (__attribute__((address_space(3))) unsigned*)lds, 16, 0, 0);
}

__device__ __forceinline__ float sigm(float x) { return 1.f / (1.f + __expf(-x)); }
__device__ __forceinline__ float tanh_f(float x) { return 2.f / (1.f + __expf(-2.f * x)) - 1.f; }

// ---------------------------------------------------------------------------
// Fused prologue: Wih/Whh/x fp32->fp16 cvt + bias sum + h-slot init, one launch.
// Work layout (float4 items): [0,1048576) Wih, [1048576,2097152) Whh,
// [2097152,6291456) x. gid<4096: bias. gid<32768: hfrag slots (slot 0 zeros =
// valid h(0) parity 0; slots 1-3 poisoned LSB=1, agent-scope).
__global__ void k_prep(const float* __restrict__ Wih, const float* __restrict__ Whh,
                       const float* __restrict__ x, const float* __restrict__ bih,
                       const float* __restrict__ bhh, _Float16* __restrict__ wih16,
                       _Float16* __restrict__ whh16, _Float16* __restrict__ x16,
                       float* __restrict__ bias, u64* __restrict__ hf) {
  const int gid = blockIdx.x * blockDim.x + threadIdx.x;
  const int stride = gridDim.x * blockDim.x;
  for (int i = gid; i < 6291456; i += stride) {
    const float* src;
    _Float16* dst;
    int k;
    if (i < 1048576) { src = Wih; dst = wih16; k = i; }
    else if (i < 2097152) { src = Whh; dst = whh16; k = i - 1048576; }
    else { src = x; dst = x16; k = i - 2097152; }
    const float4 v = ((const float4*)src)[k];
    const half4 h = {(_Float16)v.x, (_Float16)v.y, (_Float16)v.z, (_Float16)v.w};
    ((half4*)dst)[k] = h;
  }
  if (gid < 4096) bias[gid] = bih[gid] + bhh[gid];
  if (gid < 32768) {
    const u64 v = (gid < 8192) ? 0ull : 0x0001000100010001ull;
    __hip_atomic_store(&hf[gid], v, __ATOMIC_RELAXED, AGENT);
  }
}

// ---------------------------------------------------------------------------
// GEMM1: xg = x.W_ih^T + bias  (M=16384, N=4096, K=1024), fp16 out in scan
// layout [l][s][j][gate]. m97 structure w/ 16B-slot XOR swizzle (r6-verified).
__global__ __launch_bounds__(256) void k_gemm1(
    const u16* __restrict__ Aw, const u16* __restrict__ Bw,
    const float* __restrict__ bias, _Float16* __restrict__ xg) {
  __shared__ u16 sA[4096];  // 8KB: 128 rows x 32 k (64B rows, swizzled 16B slots)
  __shared__ u16 sB[4096];
  const int tid = threadIdx.x, lane = tid & 63, wid = tid >> 6;
  const int bm = blockIdx.x >> 5, bn = blockIdx.x & 31;
  const int m0 = bm * 128, n0 = bn * 128;
  const int wr = wid >> 1, wc = wid & 1;
  f32x4 acc[4][4] = {};

  for (int kt = 0; kt < 32; ++kt) {
#pragma unroll
    for (int rb = 0; rb < 2; ++rb) {  // stage A+B: 2 rounds x 1KB per wave each
      const int base = (rb * 4 + wid) * 1024;
      const int b = base + lane * 16;
      const int row = b >> 6;                       // tile row
      const int q = lane & 3;                       // 16B slot in row
      const int sq = ((q - row) & 3) << 4;          // inverse-swizzled source slot
      gl_lds16((const char*)Aw + (size_t)(m0 + row) * 2048 + (size_t)kt * 64 + sq,
               (char*)&sA[0] + base);
      gl_lds16((const char*)Bw + (size_t)(n0 + row) * 2048 + (size_t)kt * 64 + sq,
               (char*)&sB[0] + base);
    }
    __syncthreads();
    half8 ah[4], bh[4];
#pragma unroll
    for (int i = 0; i < 4; ++i) {
      const int ra = wr * 64 + i * 16 + (lane & 15);
      ah[i] = *(const half8*)((const char*)sA + ra * 64 + ((((lane >> 4) + ra) & 3) << 4));
      const int rb2 = wc * 64 + i * 16 + (lane & 15);
      bh[i] = *(const half8*)((const char*)sB + rb2 * 64 + ((((lane >> 4) + rb2) & 3) << 4));
    }
#pragma unroll
    for (int i = 0; i < 4; ++i)
#pragma unroll
      for (int j = 0; j < 4; ++j) acc[i][j] = MFMA16F(ah[i], bh[j], acc[i][j]);
    __syncthreads();
  }

  // epilogue: C/D col=lane&15, row=(lane>>4)*4+q [m89]; scatter to [l][s][j][gate]
#pragma unroll
  for (int j = 0; j < 4; ++j) {
    const int gcol = n0 + wc * 64 + j * 16 + (lane & 15);
    const int gate = gcol >> 10, jj = gcol & 1023;
    const float bv = bias[gcol];
#pragma unroll
    for (int i = 0; i < 4; ++i)
#pragma unroll
      for (int q = 0; q < 4; ++q) {
        const int m = m0 + wr * 64 + i * 16 + (lane >> 4) * 4 + q;
        const int b = m >> 11, t = m & 2047;
        const int s = (b << 2) | (t & 3);
        const int l = t >> 2;
        xg[(((size_t)(l * 32 + s)) * 1024 + jj) * 4 + gate] = (_Float16)(acc[i][j][q] + bv);
      }
  }
}

// ---------------------------------------------------------------------------
// Persistent scan v7 (r11, proven best: 2.09us/step): 4 independent groups x
// 32 WGs x 512 threads, M=8. Speculative data-as-flag: validity = LSB parity
// in the fp16 payload; 4 rotating slots; consumer stages immediately and
// retries on parity mismatch; publish = agent-scope write-through u64 pack;
// ONE __syncthreads per step; no sentinel, no flags, no grid barrier.
__global__ __launch_bounds__(512, 1) void k_scan(
    const u16* __restrict__ Whh16, const _Float16* __restrict__ xg,
    u16* __restrict__ hfrag, float* __restrict__ out) {
  __shared__ u16 h_lds[2][8192];  // 2 x 16KB double buffer
  const int tid = threadIdx.x;
  const int lane = tid & 63, wid = tid >> 6;  // 8 waves
  const int w = blockIdx.x;
  const int gr = w >> 5;         // group (0..3)
  const int wl = w & 31;         // WG id within group
  const int j0 = wl * 32;        // 32 hidden cols

  // stationary W fragments: lane p=lane&15 -> gate=p>>2, local col c=p&3;
  // wave's 4 cols are j0 + 4*wid + c. 128 VGPRs, pinned opaque.
  half8 wf[32];
  {
    const int p = lane & 15;
    const int gate = p >> 2, c = p & 3;
    const int koff = (lane >> 4) * 8;
    const size_t rowbase = (size_t)(gate * 1024 + j0 + wid * 4 + c) * 1024;
#pragma unroll
    for (int ks = 0; ks < 32; ++ks) {
      wf[ks] = *(const half8*)(Whh16 + rowbase + ks * 32 + koff);
      asm volatile("" : "+v"(wf[ks]));  // opaque: stays in register file
    }
  }

  // cell ownership (lanes 0-31 only; 32-63 hold duplicate MFMA rows)
  const int m = ((lane >> 4) << 2) | ((lane >> 2) & 3);  // chain (local, 0..7)
  const int jl = (wid << 2) | (lane & 3);                // local hidden col (0..31)
  const int s = gr * 8 + m;                              // global chain
  const int j = j0 + jl;                                 // global hidden col
  float c_reg = 0.f;
  const int hq = wl * 64 + (wid >> 1) * 16 + m * 2 + (wid & 1);

  const u64 M = 0x0001000100010001ull;

  // xg pipeline: preload step 0 (8B: 4 gates innermost), lanes 0-31
  float x0 = 0.f, x1 = 0.f, x2 = 0.f, x3 = 0.f;
  if (lane < 32) {
    const half4 xv = *(const half4*)(xg + ((size_t)s * 1024 + j) * 4);
    x0 = (float)xv[0]; x1 = (float)xv[1]; x2 = (float)xv[2]; x3 = (float)xv[3];
  }

  for (int l = 0; l < 512; ++l) {
    const char* hsrc = (const char*)hfrag + (size_t)(l & 3) * 65536 + gr * 16384;
    u64* hdst = (u64*)((char*)hfrag + (size_t)((l + 1) & 3) * 65536 + gr * 16384);
    const u64 expv = ((l >> 2) & 1) ? M : 0ull;     // expected read parity
    const u32 pw = (u32)(((l + 1) >> 2) & 1);       // publish parity
    u16* ldsb = &h_lds[l & 1][0];

    // --- speculative stage own 2KB + full parity check; retry until valid ---
    for (;;) {
#pragma unroll
      for (int r = 0; r < 2; ++r)
        gl_lds16_coh(hsrc + wid * 2048 + r * 1024 + lane * 16,
                     (char*)ldsb + wid * 2048 + r * 1024);
      asm volatile("s_waitcnt vmcnt(0)" ::: "memory");
      bool ok = true;
#pragma unroll
      for (int r = 0; r < 2; ++r) {
        const u64* q = (const u64*)((const char*)ldsb + wid * 2048 + r * 1024 + lane * 16);
        ok = ok & (((q[0] ^ expv) & M) == 0) & (((q[1] ^ expv) & M) == 0);
      }
      if (__all(ok)) break;
    }
    __syncthreads();  // the only per-step barrier

    // --- gates = h . W^T : 4 independent accumulator chains, W pinned ---
    // A-frag read: ks*512 + (lane>>4)*128 + (lane&7)*16 (rows 8-15 duplicate)
    f32x4 a0 = {0.f, 0.f, 0.f, 0.f}, a1 = a0, a2 = a0, a3 = a0;
    const char* ab = (const char*)ldsb + (lane >> 4) * 128 + (lane & 7) * 16;
#pragma unroll
    for (int ks = 0; ks < 32; ks += 4) {
      const char* cb = ab + ks * 512;
      a0 = MFMA16F(*(const half8*)(cb), wf[ks], a0);
      a1 = MFMA16F(*(const half8*)(cb + 512), wf[ks + 1], a1);
      a2 = MFMA16F(*(const half8*)(cb + 1024), wf[ks + 2], a2);
      a3 = MFMA16F(*(const half8*)(cb + 1536), wf[ks + 3], a3);
    }
    float G0 = (a0[0] + a1[0]) + (a2[0] + a3[0]);
    float G1 = (a0[1] + a1[1]) + (a2[1] + a3[1]);
    float G2 = (a0[2] + a1[2]) + (a2[2] + a3[2]);
    float G3 = (a0[3] + a1[3]) + (a2[3] + a3[3]);

    // --- 4x4 lane/register transpose (lane bits 2-3 <-> reg bits) ---
    {
      const bool h2 = (lane & 4) != 0;
      float x, y;
      x = h2 ? G0 : G1; y = __shfl_xor(x, 4);
      G0 = h2 ? y : G0; G1 = h2 ? G1 : y;
      x = h2 ? G2 : G3; y = __shfl_xor(x, 4);
      G2 = h2 ? y : G2; G3 = h2 ? G3 : y;
    }
    {
      const bool h3 = (lane & 8) != 0;
      float x, y;
      x = h3 ? G0 : G2; y = __shfl_xor(x, 8);
      G0 = h3 ? y : G0; G2 = h3 ? G2 : y;
      x = h3 ? G1 : G3; y = __shfl_xor(x, 8);
      G1 = h3 ? y : G1; G3 = h3 ? G3 : y;
    }

    // --- LSTM cell (i,f,g,o) ---
    const float gi = G0 + x0, gf = G1 + x1, gg = G2 + x2, go = G3 + x3;
    const float iv = sigm(gi), fv = sigm(gf), gv = tanh_f(gg), ov = sigm(go);
    c_reg = fv * c_reg + iv * gv;
    const float hv = ov * tanh_f(c_reg);

    if (lane < 32) {
      // --- publish FIRST (peers' critical path): parity-forced u64 pack ---
      u32 hb = (u32)__builtin_bit_cast(u16, (_Float16)hv);
      hb = (hb & 0xFFFEu) | pw;
      const u32 o1 = (u32)__shfl_xor((int)hb, 1);
      const u32 w1 = (lane & 1) ? ((o1 & 0xFFFFu) | (hb << 16))
                                : ((hb & 0xFFFFu) | (o1 << 16));
      const u32 o2lo = (u32)__shfl_xor((int)w1, 2);
      const u64 v = (lane & 2) ? (((u64)w1 << 32) | (u64)o2lo)
                               : (((u64)o2lo << 32) | (u64)w1);
      if ((lane & 3) == 0)
        __hip_atomic_store(&hdst[hq], v, __ATOMIC_RELAXED, AGENT);

      // out store (plain cached; ack overlaps next stage)
      out[(((size_t)(s >> 2) * 2048) + (size_t)l * 4 + (s & 3)) * 1024 + j] = hv;

      // next-step xg prefetch
      if (l < 511) {
        const half4 xv = *(const half4*)(xg + (((size_t)(l + 1) * 32 + s) * 1024 + j) * 4);
        x0 = (float)xv[0]; x1 = (float)xv[1]; x2 = (float)xv[2]; x3 = (float)xv[3];
      }
    }
  }
}

// ---------------------------------------------------------------------------
extern "C" void kernel_launch(void* const* d_in, const int* in_sizes, int n_in,
                              void* d_out, int out_size, void* d_ws, size_t ws_size,
                              hipStream_t stream) {
  const float* x   = (const float*)d_in[0];
  const float* Wih = (const float*)d_in[1];
  const float* Whh = (const float*)d_in[2];
  const float* bih = (const float*)d_in[3];
  const float* bhh = (const float*)d_in[4];
  float* out = (float*)d_out;
  char* ws = (char*)d_ws;

  constexpr size_t OFF_WIH16 = 0;                 //  8388608
  constexpr size_t OFF_WHH16 = 8388608;           //  8388608
  constexpr size_t OFF_BIAS  = 16777216;          //    16384
  constexpr size_t OFF_HFRAG = 16793600;          //   262144 (4 slots x 4 groups x 16KB)
  constexpr size_t OFF_XG    = 17055744;          // 134217728 (fp16)
  constexpr size_t WS_NEED   = OFF_XG + 134217728;  // 151,273,472

  if (ws_size < WS_NEED) {  // canary: absmax reads exactly 0.9140625
    hipMemsetAsync(d_out, 0, (size_t)out_size * sizeof(float), stream);
    return;
  }

  _Float16* wih16 = (_Float16*)(ws + OFF_WIH16);
  _Float16* whh16 = (_Float16*)(ws + OFF_WHH16);
  float* bias = (float*)(ws + OFF_BIAS);
  u16* hfrag = (u16*)(ws + OFF_HFRAG);
  _Float16* xg = (_Float16*)(ws + OFF_XG);
  // x16 scratch lives in d_out (67MB >= 33.5MB); scan fully overwrites out later
  _Float16* x16 = (_Float16*)d_out;

  k_prep<<<3072, 256, 0, stream>>>(Wih, Whh, x, bih, bhh, wih16, whh16, x16,
                                   bias, (u64*)hfrag);
  k_gemm1<<<4096, 256, 0, stream>>>((const u16*)x16, (const u16*)wih16, bias, xg);
  k_scan<<<128, 512, 0, stream>>>((const u16*)whh16, xg, hfrag, out);
}

// Round 19
// 1119.125 us; speedup vs baseline: 1.8086x; 1.1311x over previous
//
#include <hip/hip_runtime.h>
#include <cstdint>

typedef __attribute__((ext_vector_type(8))) _Float16 half8;  // 8 x fp16 (4 VGPRs)
typedef __attribute__((ext_vector_type(4))) _Float16 half4;  // 4 x fp16 (8B)
typedef __attribute__((ext_vector_type(4))) float f32x4;     // MFMA 16x16 accumulator
typedef unsigned short u16;
typedef unsigned int u32;
typedef unsigned long long u64;

#define MFMA16F(a, b, c) __builtin_amdgcn_mfma_f32_16x16x32_f16((a), (b), (c), 0, 0, 0)
#define AGENT __HIP_MEMORY_SCOPE_AGENT

// async global->LDS, 16B/lane. aux=17 (SC0|SC1): bypass L1+L2, read at LLC
// (r11-proven fresh vs agent WT stores; also used to keep lines OUT of L2).
__device__ __forceinline__ void gl_lds16_coh(const void* g, void* lds) {
  __builtin_amdgcn_global_load_lds(
      (const __attribute__((address_space(1))) unsigned*)g,
      (__attribute__((address_space(3))) unsigned*)lds, 16, 0, 17);
}
// cached variant (read-only data: wih16, never overwritten)
__device__ __forceinline__ void gl_lds16(const void* g, void* lds) {
  __builtin_amdgcn_global_load_lds(
      (const __attribute__((address_space(1))) unsigned*)g,
      (__attribute__((address_space(3))) unsigned*)lds, 16, 0, 0);
}

__device__ __forceinline__ float sigm(float x) { return 1.f / (1.f + __expf(-x)); }
__device__ __forceinline__ float tanh_f(float x) { return 2.f / (1.f + __expf(-2.f * x)) - 1.f; }

// ---------------------------------------------------------------------------
// Fused prologue: weight/x fp32->fp16 cvt (x into per-slab chunks), bias sum,
// h-slot init, slab-counter zero. One launch.
__global__ void k_prep(const float* __restrict__ Wih, const float* __restrict__ Whh,
                       const float* __restrict__ x, const float* __restrict__ bih,
                       const float* __restrict__ bhh, _Float16* __restrict__ wih16,
                       _Float16* __restrict__ whh16, _Float16* __restrict__ x16lo,
                       _Float16* __restrict__ x16hi, float* __restrict__ bias,
                       u64* __restrict__ hf, u32* __restrict__ slabcnt) {
  const int gid = blockIdx.x * blockDim.x + threadIdx.x;
  const int stride = gridDim.x * blockDim.x;
  for (int i = gid; i < 6291456; i += stride) {
    if (i < 2097152) {
      const float* src = (i < 1048576) ? Wih : Whh;
      _Float16* dst = (i < 1048576) ? wih16 : whh16;
      const int k = i & 1048575;
      const float4 v = ((const float4*)src)[k];
      const half4 h = {(_Float16)v.x, (_Float16)v.y, (_Float16)v.z, (_Float16)v.w};
      ((half4*)dst)[k] = h;
    } else {
      // x -> chunked fp16: chunk sig holds rows t in [128*sig,+128) of all batches
      const int k4 = i - 2097152;
      const float4 v = ((const float4*)x)[k4];
      const int mm = k4 >> 8, c4 = k4 & 255;     // row m, float4 col
      const int b = mm >> 11, t = mm & 2047;
      const int sig = t >> 7, rl = t & 127;
      _Float16* dst = (sig < 8) ? (x16lo + (size_t)sig * 4194304)
                                : (x16hi + (size_t)(sig - 8) * 1048576);
      const half4 h = {(_Float16)v.x, (_Float16)v.y, (_Float16)v.z, (_Float16)v.w};
      ((half4*)dst)[(size_t)(b * 128 + rl) * 256 + c4] = h;
    }
  }
  if (gid < 4096) bias[gid] = bih[gid] + bhh[gid];
  if (gid < 32768) {
    const u64 v = (gid < 8192) ? 0ull : 0x0001000100010001ull;
    __hip_atomic_store(&hf[gid], v, __ATOMIC_RELAXED, AGENT);
  }
  if (gid < 16) __hip_atomic_store(&slabcnt[gid], 0u, __ATOMIC_RELAXED, AGENT);
}

// ---------------------------------------------------------------------------
// Fused scan+GEMM. Blocks 0..127: persistent scan (r18-verbatim hot loop +
// slab gating). Blocks 128..4223: GEMM tiles in slab order; xg written via
// WT-to-LLC short stores; per-slab completion counter gates the scan.
__global__ __launch_bounds__(512, 1) void k_fused(
    const u16* __restrict__ x16lo, const u16* __restrict__ x16hi,
    const u16* __restrict__ Bw, const float* __restrict__ bias,
    _Float16* __restrict__ xg, const u16* __restrict__ Whh16,
    u16* __restrict__ hfrag, float* __restrict__ out, u32* __restrict__ slabcnt) {
  __shared__ u16 smem[16384];  // 32KB: scan h dbuf / gemm 2x(sA+sB)
  const int tid = threadIdx.x;
  const int lane = tid & 63, wid = tid >> 6;  // 8 waves

  if (blockIdx.x >= 128) {
    // ------------------------- GEMM path -------------------------
    const int bidx = blockIdx.x - 128;
    const int sigma = bidx >> 8;        // l-slab 0..15, dispatch-ordered
    const int bb = (bidx >> 5) & 7;     // batch
    const int bn = bidx & 31;
    const int n0 = bn * 128;
    const int wr = wid >> 1, wc = wid & 1;   // M-quarter (32 rows), N-half
    const u16* Ach = (sigma < 8) ? (x16lo + (size_t)sigma * 4194304)
                                 : (x16hi + (size_t)(sigma - 8) * 1048576);
    f32x4 acc[2][4] = {};

    // per-thread staging address (1KB/wave per operand; 16B-slot XOR swizzle)
    const int sbase = wid * 1024;
    const int soff = sbase + lane * 16;
    const int srow = soff >> 6;
    const int sq = (((lane & 3) - srow) & 3) << 4;
    const char* asrc = (const char*)Ach + (size_t)(bb * 128 + srow) * 2048 + sq;
    const char* bsrc = (const char*)Bw + (size_t)(n0 + srow) * 2048 + sq;

    // prologue: stage kt=0 into buf0
    gl_lds16_coh(asrc, (char*)smem + sbase);                  // A: LLC-direct
    gl_lds16(bsrc, (char*)(smem + 4096) + sbase);             // B: cached
    asm volatile("s_waitcnt vmcnt(0)" ::: "memory");
    __syncthreads();

    for (int kt = 0; kt < 32; ++kt) {
      const int cur = kt & 1;
      if (kt < 31) {  // stage kt+1 into the other buffer (hidden under MFMA)
        const size_t ko = (size_t)(kt + 1) * 64;
        gl_lds16_coh(asrc + ko, (char*)(smem + (cur ^ 1) * 8192) + sbase);
        gl_lds16(bsrc + ko, (char*)(smem + (cur ^ 1) * 8192 + 4096) + sbase);
      }
      const u16* sA = smem + cur * 8192;
      const u16* sB = sA + 4096;
      half8 ah[2], bh4[4];
#pragma unroll
      for (int i = 0; i < 2; ++i) {
        const int ra = wr * 32 + i * 16 + (lane & 15);
        ah[i] = *(const half8*)((const char*)sA + ra * 64 + ((((lane >> 4) + ra) & 3) << 4));
      }
#pragma unroll
      for (int j = 0; j < 4; ++j) {
        const int rb = wc * 64 + j * 16 + (lane & 15);
        bh4[j] = *(const half8*)((const char*)sB + rb * 64 + ((((lane >> 4) + rb) & 3) << 4));
      }
#pragma unroll
      for (int i = 0; i < 2; ++i)
#pragma unroll
        for (int j = 0; j < 4; ++j) acc[i][j] = MFMA16F(ah[i], bh4[j], acc[i][j]);
      asm volatile("s_waitcnt vmcnt(0)" ::: "memory");
      __syncthreads();
    }

    // epilogue: WT-to-LLC short stores, drain, then slab counter
    const int m0 = (bb * 16 + sigma) * 128;
#pragma unroll
    for (int j = 0; j < 4; ++j) {
      const int gcol = n0 + wc * 64 + j * 16 + (lane & 15);
      const int gate = gcol >> 10, jj = gcol & 1023;
      const float bv = bias[gcol];
#pragma unroll
      for (int i = 0; i < 2; ++i)
#pragma unroll
        for (int q = 0; q < 4; ++q) {
          const int m = m0 + wr * 32 + i * 16 + (lane >> 4) * 4 + q;
          const int b = m >> 11, t = m & 2047;
          const int s = (b << 2) | (t & 3);
          const int l = t >> 2;
          const _Float16 hv = (_Float16)(acc[i][j][q] + bv);
          _Float16* addr = xg + (((size_t)(l * 32 + s)) * 1024 + jj) * 4 + gate;
          asm volatile("global_store_short %0, %1, off sc0 sc1"
                       :: "v"(addr), "v"((u32)__builtin_bit_cast(u16, hv)) : "memory");
        }
    }
    asm volatile("s_waitcnt vmcnt(0)" ::: "memory");
    __syncthreads();
    if (tid == 0)
      __hip_atomic_fetch_add(&slabcnt[sigma], 1u, __ATOMIC_RELAXED, AGENT);
    return;
  }

  // ------------------------- scan path (r18 + gating) -------------------------
  const int w = blockIdx.x;
  const int gr = w >> 5;         // group (0..3)
  const int wl = w & 31;         // WG id within group
  const int j0 = wl * 32;        // 32 hidden cols

  half8 wf[32];
  {
    const int p = lane & 15;
    const int gate = p >> 2, c = p & 3;
    const int koff = (lane >> 4) * 8;
    const size_t rowbase = (size_t)(gate * 1024 + j0 + wid * 4 + c) * 1024;
#pragma unroll
    for (int ks = 0; ks < 32; ++ks) {
      wf[ks] = *(const half8*)((const _Float16*)Whh16 + rowbase + ks * 32 + koff);
      asm volatile("" : "+v"(wf[ks]));  // opaque: stays in register file
    }
  }

  const int m = ((lane >> 4) << 2) | ((lane >> 2) & 3);  // chain (local, 0..7)
  const int jl = (wid << 2) | (lane & 3);                // local hidden col
  const int s = gr * 8 + m;                              // global chain
  const int j = j0 + jl;                                 // global hidden col
  float c_reg = 0.f;
  const int hq = wl * 64 + (wid >> 1) * 16 + m * 2 + (wid & 1);

  const u64 M = 0x0001000100010001ull;

  // xg preload step 0, gated on slab 0 completion
  float x0 = 0.f, x1 = 0.f, x2 = 0.f, x3 = 0.f;
  if (lane < 32) {
    while (__hip_atomic_load(&slabcnt[0], __ATOMIC_RELAXED, AGENT) < 256u)
      __builtin_amdgcn_s_sleep(1);
    const half4 xv = *(const half4*)(xg + ((size_t)s * 1024 + j) * 4);
    x0 = (float)xv[0]; x1 = (float)xv[1]; x2 = (float)xv[2]; x3 = (float)xv[3];
  }

  for (int l = 0; l < 512; ++l) {
    const char* hsrc = (const char*)hfrag + (size_t)(l & 3) * 65536 + gr * 16384;
    u64* hdst = (u64*)((char*)hfrag + (size_t)((l + 1) & 3) * 65536 + gr * 16384);
    const u64 expv = ((l >> 2) & 1) ? M : 0ull;
    const u32 pw = (u32)(((l + 1) >> 2) & 1);
    u16* ldsb = smem + (l & 1) * 8192;

    // speculative stage own 2KB + full parity check; retry until valid
    for (;;) {
#pragma unroll
      for (int r = 0; r < 2; ++r)
        gl_lds16_coh(hsrc + wid * 2048 + r * 1024 + lane * 16,
                     (char*)ldsb + wid * 2048 + r * 1024);
      asm volatile("s_waitcnt vmcnt(0)" ::: "memory");
      bool ok = true;
#pragma unroll
      for (int r = 0; r < 2; ++r) {
        const u64* q = (const u64*)((const char*)ldsb + wid * 2048 + r * 1024 + lane * 16);
        ok = ok & (((q[0] ^ expv) & M) == 0) & (((q[1] ^ expv) & M) == 0);
      }
      if (__all(ok)) break;
    }
    __syncthreads();  // the only per-step barrier

    f32x4 a0 = {0.f, 0.f, 0.f, 0.f}, a1 = a0, a2 = a0, a3 = a0;
    const char* ab = (const char*)ldsb + (lane >> 4) * 128 + (lane & 7) * 16;
#pragma unroll
    for (int ks = 0; ks < 32; ks += 4) {
      const char* cb = ab + ks * 512;
      a0 = MFMA16F(*(const half8*)(cb), wf[ks], a0);
      a1 = MFMA16F(*(const half8*)(cb + 512), wf[ks + 1], a1);
      a2 = MFMA16F(*(const half8*)(cb + 1024), wf[ks + 2], a2);
      a3 = MFMA16F(*(const half8*)(cb + 1536), wf[ks + 3], a3);
    }
    float G0 = (a0[0] + a1[0]) + (a2[0] + a3[0]);
    float G1 = (a0[1] + a1[1]) + (a2[1] + a3[1]);
    float G2 = (a0[2] + a1[2]) + (a2[2] + a3[2]);
    float G3 = (a0[3] + a1[3]) + (a2[3] + a3[3]);

    {  // 4x4 lane/register transpose (lane bits 2-3 <-> reg bits)
      const bool h2 = (lane & 4) != 0;
      float x, y;
      x = h2 ? G0 : G1; y = __shfl_xor(x, 4);
      G0 = h2 ? y : G0; G1 = h2 ? G1 : y;
      x = h2 ? G2 : G3; y = __shfl_xor(x, 4);
      G2 = h2 ? y : G2; G3 = h2 ? G3 : y;
    }
    {
      const bool h3 = (lane & 8) != 0;
      float x, y;
      x = h3 ? G0 : G2; y = __shfl_xor(x, 8);
      G0 = h3 ? y : G0; G2 = h3 ? G2 : y;
      x = h3 ? G1 : G3; y = __shfl_xor(x, 8);
      G1 = h3 ? y : G1; G3 = h3 ? G3 : y;
    }

    const float gi = G0 + x0, gf = G1 + x1, gg = G2 + x2, go = G3 + x3;
    const float iv = sigm(gi), fv = sigm(gf), gv = tanh_f(gg), ov = sigm(go);
    c_reg = fv * c_reg + iv * gv;
    const float hv = ov * tanh_f(c_reg);

    if (lane < 32) {
      // publish FIRST: parity-forced u64 pack, agent write-through
      u32 hb = (u32)__builtin_bit_cast(u16, (_Float16)hv);
      hb = (hb & 0xFFFEu) | pw;
      const u32 o1 = (u32)__shfl_xor((int)hb, 1);
      const u32 w1 = (lane & 1) ? ((o1 & 0xFFFFu) | (hb << 16))
                                : ((hb & 0xFFFFu) | (o1 << 16));
      const u32 o2lo = (u32)__shfl_xor((int)w1, 2);
      const u64 v = (lane & 2) ? (((u64)w1 << 32) | (u64)o2lo)
                               : (((u64)o2lo << 32) | (u64)w1);
      if ((lane & 3) == 0)
        __hip_atomic_store(&hdst[hq], v, __ATOMIC_RELAXED, AGENT);

      out[(((size_t)(s >> 2) * 2048) + (size_t)l * 4 + (s & 3)) * 1024 + j] = hv;

      if (l < 511) {
        if (((l + 1) & 31) == 0) {  // crossing into a new xg slab: gate on producer
          while (__hip_atomic_load(&slabcnt[(l + 1) >> 5], __ATOMIC_RELAXED, AGENT) < 256u)
            __builtin_amdgcn_s_sleep(1);
        }
        const half4 xv = *(const half4*)(xg + (((size_t)(l + 1) * 32 + s) * 1024 + j) * 4);
        x0 = (float)xv[0]; x1 = (float)xv[1]; x2 = (float)xv[2]; x3 = (float)xv[3];
      }
    }
  }
}

// ---------------------------------------------------------------------------
extern "C" void kernel_launch(void* const* d_in, const int* in_sizes, int n_in,
                              void* d_out, int out_size, void* d_ws, size_t ws_size,
                              hipStream_t stream) {
  const float* x   = (const float*)d_in[0];
  const float* Wih = (const float*)d_in[1];
  const float* Whh = (const float*)d_in[2];
  const float* bih = (const float*)d_in[3];
  const float* bhh = (const float*)d_in[4];
  float* out = (float*)d_out;
  char* ws = (char*)d_ws;

  constexpr size_t OFF_WIH16 = 0;                 //   8388608
  constexpr size_t OFF_WHH16 = 8388608;           //   8388608
  constexpr size_t OFF_BIAS  = 16777216;          //     16384
  constexpr size_t OFF_HFRAG = 16793600;          //    262144 (4 slots x 4 groups x 16KB)
  constexpr size_t OFF_SLAB  = 17055744;          //        64
  constexpr size_t OFF_XG    = 17055808;          // 134217728 (fp16)
  // x16 chunks 0-7 live inside xg slabs 8-15 (read at time sig, overwritten at
  // time 8+sig >> sig); chunks 8-15 in dedicated tail:
  constexpr size_t OFF_X16HI = OFF_XG + 134217728;   //  16777216
  constexpr size_t WS_NEED   = OFF_X16HI + 16777216; // 168,050,752 (< r2-proven 168,869,888)

  if (ws_size < WS_NEED) {  // canary: absmax reads exactly 0.9140625
    hipMemsetAsync(d_out, 0, (size_t)out_size * sizeof(float), stream);
    return;
  }

  _Float16* wih16 = (_Float16*)(ws + OFF_WIH16);
  _Float16* whh16 = (_Float16*)(ws + OFF_WHH16);
  float* bias = (float*)(ws + OFF_BIAS);
  u16* hfrag = (u16*)(ws + OFF_HFRAG);
  u32* slabcnt = (u32*)(ws + OFF_SLAB);
  _Float16* xg = (_Float16*)(ws + OFF_XG);
  _Float16* x16lo = (_Float16*)(ws + OFF_XG + 8ull * 8388608);  // xg slab-8 start
  _Float16* x16hi = (_Float16*)(ws + OFF_X16HI);

  k_prep<<<3072, 256, 0, stream>>>(Wih, Whh, x, bih, bhh, wih16, whh16,
                                   x16lo, x16hi, bias, (u64*)hfrag, slabcnt);
  k_fused<<<128 + 4096, 512, 0, stream>>>((const u16*)x16lo, (const u16*)x16hi,
                                          (const u16*)wih16, bias, xg,
                                          (const u16*)whh16, hfrag, out, slabcnt);
}